// Round 1
// baseline (5919.641 us; speedup 1.0000x reference)
//
#include <hip/hip_runtime.h>
#include <math.h>

// Problem constants
// B=512, D_MODEL=1024, D_INNER=2048, 2*D_INNER=4096, DT_RANK=64, D_STATE=64,
// NBC = DT_RANK+2*D_STATE = 192, C_OUT=64, PRED_LEN=96

__device__ __forceinline__ float silu_f(float v){ return v / (1.0f + expf(-v)); }

// ---------------- setup kernels (run once per launch) ----------------

// ctx_xz[b][j] = b_in[j] + sum_k context[b][k] * w_in[k][j]   (M=512,N=4096,K=1024)
// grid (16 j-tiles of 256, 32 rowgroups of 16), block 256
__global__ void k_ctx(const float* __restrict__ ctxin, const float* __restrict__ w_in,
                      const float* __restrict__ b_in, float* __restrict__ ctx_xz){
  __shared__ float ctxL[16][128];
  int tid = threadIdx.x;
  int j = blockIdx.x*256 + tid;
  int b0 = blockIdx.y*16;
  float acc[16];
#pragma unroll
  for (int r=0;r<16;r++) acc[r]=0.f;
  for (int kc=0;kc<1024;kc+=128){
    __syncthreads();
#pragma unroll
    for (int i=0;i<8;i++){
      int idx = i*256+tid;
      int r = idx>>7, kk = idx&127;
      ctxL[r][kk] = ctxin[(b0+r)*1024 + kc + kk];
    }
    __syncthreads();
    for (int kk=0;kk<128;kk++){
      float w = w_in[(size_t)(kc+kk)*4096 + j];
#pragma unroll
      for (int r=0;r<16;r++) acc[r] += ctxL[r][kk]*w;
    }
  }
  float bj = b_in[j];
#pragma unroll
  for (int r=0;r<16;r++) ctx_xz[(size_t)(b0+r)*4096 + j] = acc[r] + bj;
}

// W_op = w_out @ w_proj  [2048,64], b_op = b_out @ w_proj + b_proj [64]
// grid 513 blocks x 256
__global__ void k_wop(const float* __restrict__ w_out, const float* __restrict__ w_proj,
                      const float* __restrict__ b_out, const float* __restrict__ b_proj,
                      float* __restrict__ W_op, float* __restrict__ b_op){
  int g = blockIdx.x;
  int tid = threadIdx.x;
  if (g == 512){
    if (tid < 64){
      float s = b_proj[tid];
      for (int k=0;k<1024;k++) s += b_out[k]*w_proj[k*64+tid];
      b_op[tid] = s;
    }
    return;
  }
  int idx = g*256 + tid;
  int c = idx>>6, o = idx&63;
  float s = 0.f;
  const float* wr = w_out + (size_t)c*1024;
  for (int k=0;k<1024;k++) s += wr[k]*w_proj[k*64+o];
  W_op[idx] = s;
}

__global__ void k_zero(float* __restrict__ p, int n){
  int i = blockIdx.x*256 + threadIdx.x;
  if (i < n) p[i] = 0.f;
}

// ---------------- per-step kernels ----------------

// K1: xz = ctx_xz + pred_prev @ w_in2 ; x = silu(conv(xz_lo)); sz = silu(xz_hi)
//     + K-split atomic accumulation of xdbc = x @ w_x  (each j-tile contributes)
//     + writes d_out for step t-1 (bx==0), zeroes pa_cur (bx==1)
// grid (16 j-tiles, 32 rowgroups of 16), block 256
__global__ void k_step1(const float* __restrict__ ctx_xz, const float* __restrict__ w_in2,
                        const float* __restrict__ conv_w, const float* __restrict__ conv_b,
                        const float* __restrict__ w_x,
                        const float* __restrict__ pred_prev,
                        const float* __restrict__ b_op,
                        float* __restrict__ xbuf, float* __restrict__ szbuf,
                        float* __restrict__ xdbc_cur, float* __restrict__ pa_cur,
                        float* __restrict__ dout, int t)
{
  __shared__ float predL[16][64];
  __shared__ float xtile[16][256];
  int tid = threadIdx.x;
  int bx = blockIdx.x, by = blockIdx.y;
  int b0 = by*16;
  int j = bx*256 + tid;

#pragma unroll
  for (int i=0;i<4;i++){
    int idx = i*256 + tid;
    int r = idx>>6, o = idx&63;
    float v = pred_prev[(b0+r)*64 + o];
    if (t != 0) v += b_op[o];
    predL[r][o] = v;
    if (t > 0 && bx == 0)
      dout[((size_t)(b0+r)*96 + (t-1))*64 + o] = v;
  }
  if (bx == 1){
#pragma unroll
    for (int i=0;i<4;i++) pa_cur[b0*64 + i*256 + tid] = 0.f;
  }
  __syncthreads();

  float acc[16];
#pragma unroll
  for (int r=0;r<16;r++) acc[r] = ctx_xz[(size_t)(b0+r)*4096 + j];
  for (int o=0;o<64;o++){
    float w = w_in2[o*4096 + j];
#pragma unroll
    for (int r=0;r<16;r++) acc[r] += predL[r][o]*w;
  }

  if (bx < 8){ // x half: conv scale + silu, stage for xdbc partial GEMM
    float cw = conv_w[j*4+3], cb = conv_b[j];
#pragma unroll
    for (int r=0;r<16;r++){
      float v = acc[r]*cw + cb;
      float s = silu_f(v);
      xbuf[(b0+r)*2048 + j] = s;
      xtile[r][tid] = s;
    }
    __syncthreads();
    if (tid < 192){
      float facc[16];
#pragma unroll
      for (int r=0;r<16;r++) facc[r]=0.f;
      int j0 = bx*256;
      for (int jj=0;jj<256;jj++){
        float w = w_x[(j0+jj)*192 + tid];
#pragma unroll
        for (int r=0;r<16;r++) facc[r] += xtile[r][jj]*w;
      }
#pragma unroll
      for (int r=0;r<16;r++) atomicAdd(&xdbc_cur[(b0+r)*192 + tid], facc[r]);
    }
  } else { // z half: silu only
    int jz = j - 2048;
#pragma unroll
    for (int r=0;r<16;r++){
      szbuf[(b0+r)*2048 + jz] = silu_f(acc[r]);
    }
  }
}

// K2: dt = softplus(xdbc[:, :64] @ w_dt + b_dt); bc = sum(Bm*Cm);
//     y = (dt*bc + D_skip) * x * sz ; pred partial = y @ W_op (atomic)
//     also zeroes the other xdbc parity (ct==0) for next step's K1
// grid (8 c-tiles of 256, 32 rowgroups of 16), block 256
__global__ void k_step2(const float* __restrict__ xbuf, const float* __restrict__ szbuf,
                        const float* __restrict__ xdbc_cur, float* __restrict__ xdbc_next,
                        const float* __restrict__ w_dt, const float* __restrict__ b_dt,
                        const float* __restrict__ D_skip, const float* __restrict__ W_op,
                        float* __restrict__ pa_cur)
{
  __shared__ float xdbcL[16][192];
  __shared__ float bcL[16];
  __shared__ float yL[16][256];
  __shared__ float redL[16*256];
  int tid = threadIdx.x;
  int ct = blockIdx.x, by = blockIdx.y;
  int b0 = by*16, c0 = ct*256;

#pragma unroll
  for (int i=0;i<12;i++){
    int idx = i*256 + tid;
    int r = idx/192, n = idx%192;
    xdbcL[r][n] = xdbc_cur[(b0+r)*192 + n];
  }
  if (ct == 0){
#pragma unroll
    for (int i=0;i<12;i++) xdbc_next[b0*192 + i*256 + tid] = 0.f;
  }
  __syncthreads();
  if (tid < 16){
    float s = 0.f;
#pragma unroll
    for (int i=0;i<64;i++) s += xdbcL[tid][64+i]*xdbcL[tid][128+i];
    bcL[tid] = s;
  }
  __syncthreads();

  int c = c0 + tid;
  float acc[16];
#pragma unroll
  for (int r=0;r<16;r++) acc[r]=0.f;
  for (int o=0;o<64;o++){
    float w = w_dt[o*2048 + c];
#pragma unroll
    for (int r=0;r<16;r++) acc[r] += xdbcL[r][o]*w;
  }
  float bdt = b_dt[c], dsk = D_skip[c];
#pragma unroll
  for (int r=0;r<16;r++){
    float v = acc[r] + bdt;
    float dt = log1pf(expf(v));   // softplus
    float xv = xbuf[(b0+r)*2048 + c];
    float zv = szbuf[(b0+r)*2048 + c];
    yL[r][tid] = (dt*bcL[r] + dsk) * xv * zv;
  }
  __syncthreads();

  // pred partial: thread (o = tid&63, ks = tid>>6) covers k = ks*64 .. +63
  int o = tid & 63, ks = tid >> 6;
  float pacc[16];
#pragma unroll
  for (int r=0;r<16;r++) pacc[r]=0.f;
  for (int kk=0;kk<64;kk++){
    int k = ks*64 + kk;
    float w = W_op[(c0+k)*64 + o];
#pragma unroll
    for (int r=0;r<16;r++) pacc[r] += yL[r][k]*w;
  }
#pragma unroll
  for (int r=0;r<16;r++) redL[r*256 + tid] = pacc[r];
  __syncthreads();
#pragma unroll
  for (int i=0;i<4;i++){
    int idx = i*256 + tid;
    int r = idx>>6, oo = idx&63;
    float s = redL[r*256 + oo] + redL[r*256 + 64 + oo]
            + redL[r*256 + 128 + oo] + redL[r*256 + 192 + oo];
    atomicAdd(&pa_cur[(b0+r)*64 + oo], s);
  }
}

// final step's pred -> d_out
__global__ void k_final(const float* __restrict__ pa, const float* __restrict__ b_op,
                        float* __restrict__ dout){
  int idx = blockIdx.x*256 + threadIdx.x;
  int b = idx>>6, o = idx&63;
  dout[((size_t)b*96 + 95)*64 + o] = pa[idx] + b_op[o];
}

// ---------------- launch ----------------

extern "C" void kernel_launch(void* const* d_in, const int* in_sizes, int n_in,
                              void* d_out, int out_size, void* d_ws, size_t ws_size,
                              hipStream_t stream)
{
  const float* context = (const float*)d_in[0];
  const float* initial = (const float*)d_in[1];
  const float* w_in    = (const float*)d_in[2];
  const float* b_in    = (const float*)d_in[3];
  const float* conv_w  = (const float*)d_in[4];
  const float* conv_b  = (const float*)d_in[5];
  const float* w_x     = (const float*)d_in[6];
  const float* w_dt    = (const float*)d_in[7];
  const float* b_dt    = (const float*)d_in[8];
  // d_in[9] = A_log (unused with L=1, h0=0)
  const float* D_skip  = (const float*)d_in[10];
  const float* w_out   = (const float*)d_in[11];
  const float* b_out   = (const float*)d_in[12];
  const float* w_proj  = (const float*)d_in[13];
  const float* b_proj  = (const float*)d_in[14];

  float* ws = (float*)d_ws;
  float* ctx_xz = ws;                    // 512*4096  = 2097152
  float* W_op   = ctx_xz + 2097152;      // 2048*64   = 131072
  float* b_op   = W_op + 131072;         // 64 (pad to 128)
  float* xbuf   = b_op + 128;            // 512*2048  = 1048576
  float* szbuf  = xbuf + 1048576;        // 512*2048  = 1048576
  float* xdbc0  = szbuf + 1048576;       // 512*192   = 98304
  float* xdbc1  = xdbc0 + 98304;         // 98304
  float* pa0    = xdbc1 + 98304;         // 512*64    = 32768
  float* pa1    = pa0 + 32768;           // 32768
  float* dout   = (float*)d_out;

  k_ctx <<<dim3(16,32), 256, 0, stream>>>(context, w_in, b_in, ctx_xz);
  k_wop <<<dim3(513),   256, 0, stream>>>(w_out, w_proj, b_out, b_proj, W_op, b_op);
  k_zero<<<dim3(384),   256, 0, stream>>>(xdbc0, 98304);

  const float* w_in2 = w_in + 1024*4096;

  for (int t = 0; t < 96; t++){
    float* xd_cur = (t & 1) ? xdbc1 : xdbc0;
    float* xd_nxt = (t & 1) ? xdbc0 : xdbc1;
    float* pacur  = (t & 1) ? pa1 : pa0;
    const float* ppred = (t == 0) ? initial : ((t & 1) ? (const float*)pa0 : (const float*)pa1);

    k_step1<<<dim3(16,32), 256, 0, stream>>>(ctx_xz, w_in2, conv_w, conv_b, w_x,
                                             ppred, b_op, xbuf, szbuf,
                                             xd_cur, pacur, dout, t);
    k_step2<<<dim3(8,32), 256, 0, stream>>>(xbuf, szbuf, xd_cur, xd_nxt,
                                            w_dt, b_dt, D_skip, W_op, pacur);
  }
  k_final<<<dim3(128), 256, 0, stream>>>(pa1, b_op, dout);
}

// Round 2
// 4282.737 us; speedup vs baseline: 1.3822x; 1.3822x over previous
//
#include <hip/hip_runtime.h>
#include <math.h>

// B=512, D_MODEL=1024, D_INNER=2048, DT_RANK=64, D_STATE=64, NBC=192,
// C_OUT=64, PRED_LEN=96.
// Persistent-kernel design: grid = 256 blocks x 512 threads (<=1 block/CU ->
// all blocks guaranteed co-resident; no cooperative launch needed).
// 16 groups (batch tiles of 32 rows) x 16 blocks (col tiles of 128).
// Group-local barriers via device-scope atomic counters; all cross-block data
// moves through device-scope atomics (adds/loads), so no acquire-fence L2
// invalidation is needed (MALL is the single serialization point).

#define AGENT __HIP_MEMORY_SCOPE_AGENT

__device__ __forceinline__ float sigf(float v){
  return __builtin_amdgcn_rcpf(1.f + __expf(-v));
}

// ---------------- setup kernels ----------------

// ctx_xz[b][j] = b_in[j] + sum_k context[b][k]*w_in[k][j]  (512x4096, K=1024)
// wave-uniform ctx reads -> scalar loads; no LDS.
__global__ __launch_bounds__(256) void k_ctx(
    const float* __restrict__ ctxin, const float* __restrict__ w_in,
    const float* __restrict__ b_in, float* __restrict__ ctx_xz){
  int tid = threadIdx.x;
  int j = blockIdx.x*256 + tid;
  int b0 = blockIdx.y*16;
  const float* cp = ctxin + (size_t)b0*1024;
  float acc[16];
#pragma unroll
  for (int r=0;r<16;r++) acc[r]=0.f;
  for (int k=0;k<1024;k+=4){
    float w0 = w_in[(size_t)(k+0)*4096 + j];
    float w1 = w_in[(size_t)(k+1)*4096 + j];
    float w2 = w_in[(size_t)(k+2)*4096 + j];
    float w3 = w_in[(size_t)(k+3)*4096 + j];
#pragma unroll
    for (int r=0;r<16;r++){
      acc[r] += cp[r*1024+k]*w0 + cp[r*1024+k+1]*w1
              + cp[r*1024+k+2]*w2 + cp[r*1024+k+3]*w3;
    }
  }
  float bj = b_in[j];
#pragma unroll
  for (int r=0;r<16;r++) ctx_xz[(size_t)(b0+r)*4096 + j] = acc[r] + bj;
}

// W_op = w_out @ w_proj [2048,64]; b_op = b_out @ w_proj + b_proj [64]
__global__ __launch_bounds__(256) void k_wop(
    const float* __restrict__ w_out, const float* __restrict__ w_proj,
    const float* __restrict__ b_out, const float* __restrict__ b_proj,
    float* __restrict__ W_op, float* __restrict__ b_op){
  int g = blockIdx.x, tid = threadIdx.x;
  if (g == 512){
    if (tid < 64){
      float s = b_proj[tid];
      for (int k=0;k<1024;k++) s += b_out[k]*w_proj[k*64+tid];
      b_op[tid] = s;
    }
    return;
  }
  int idx = g*256 + tid;
  int c = idx>>6, o = idx&63;
  float s = 0.f;
  const float* wr = w_out + (size_t)c*1024;
  for (int k=0;k<1024;k++) s += wr[k]*w_proj[k*64+o];
  W_op[idx] = s;
}

// cvec[j] = sum_o b_op[o]*w_in2[o][j]   (folds b_op into the xz update)
__global__ __launch_bounds__(256) void k_cvec(
    const float* __restrict__ b_op, const float* __restrict__ w_in2,
    float* __restrict__ cvec){
  int j = blockIdx.x*256 + threadIdx.x;
  float s = 0.f;
  for (int o=0;o<64;o++) s += b_op[o]*w_in2[(size_t)o*4096 + j];
  cvec[j] = s;
}

__global__ void k_zero(float* __restrict__ p, int n){
  int i = blockIdx.x*256 + threadIdx.x;
  if (i < n) p[i] = 0.f;
}

// ---------------- persistent step kernel ----------------

__device__ __forceinline__ void gbar(int* flag, int target){
  __syncthreads();             // compiler emits vmcnt(0) drain before s_barrier
  if (threadIdx.x == 0){
    __hip_atomic_fetch_add(flag, 1, __ATOMIC_RELEASE, AGENT);
    while (__hip_atomic_load(flag, __ATOMIC_RELAXED, AGENT) < target)
      __builtin_amdgcn_s_sleep(1);
    (void)__hip_atomic_load(flag, __ATOMIC_ACQUIRE, __HIP_MEMORY_SCOPE_WORKGROUP);
  }
  __syncthreads();
}

__global__ __launch_bounds__(512,2) void k_steps(
    const float* __restrict__ ctx_xz, const float* __restrict__ cvec,
    const float* __restrict__ w_in2,  const float* __restrict__ conv_w,
    const float* __restrict__ conv_b, const float* __restrict__ w_x,
    const float* __restrict__ w_dt,   const float* __restrict__ b_dt,
    const float* __restrict__ D_skip, const float* __restrict__ W_op,
    const float* __restrict__ b_op,   const float* __restrict__ initial,
    float* __restrict__ xd0, float* __restrict__ xd1,
    float* __restrict__ pa0, float* __restrict__ pa1,
    int* __restrict__ flags, float* __restrict__ dout)
{
  const int tid  = threadIdx.x;
  const int bt   = blockIdx.x & 15;   // group (32 batch rows); XCD-local if %8 round-robin
  const int tile = blockIdx.x >> 4;   // 0..15, 128 cols each
  const int lane = tid & 63;
  const int half = tid >> 8;          // two 64-col halves
  const int wq   = (tid >> 6) & 3;    // 8-row group for compute stages
  const int rq   = tid >> 6;          // 0..7: 4-row group for full-K reductions
  const int r0   = bt * 32;
  const int rb8  = wq * 8;
  const int jx   = tile*128 + half*64 + lane;   // x / c column (0..2047)
  const int jz   = 2048 + jx;                   // z column in xz space

  __shared__ float predT[64][36];   // [o][row], padded for b128 alignment
  __shared__ float xT[128][36];     // phase A: x-tile [j][row]; phase C: xdbcT [o][row] (first 64)
  __shared__ float yT[128][36];     // [c][row]
  __shared__ float bcL[32];

  // step-invariant register preloads
  const float cw  = conv_w[jx*4+3];
  const float cb  = conv_b[jx];
  const float cvx = cvec[jx];
  const float cvz = cvec[jz];
  const float bdt = b_dt[jx];
  const float dsk = D_skip[jx];
  const float bop = b_op[lane];
  float ctxv[8], ctzv[8];
#pragma unroll
  for (int r=0;r<8;r++){
    ctxv[r] = ctx_xz[(size_t)(r0+rb8+r)*4096 + jx];
    ctzv[r] = ctx_xz[(size_t)(r0+rb8+r)*4096 + jz];
  }
  int* flag = flags + bt*32;   // 128B-separated counters

  for (int t=0; t<96; t++){
    const float* pin = (t&1) ? pa1 : pa0;   // OUT(t-1)
    float*       pout= (t&1) ? pa0 : pa1;   // OUT(t)
    float*       xdc = (t&1) ? xd1 : xd0;
    float*       xdn = (t&1) ? xd0 : xd1;

    // ---- Phase A: stage pred, compute x, xdbc partials ----
#pragma unroll
    for (int i=0;i<4;i++){
      int row = i*8 + rq;                 // 0..31 ; o == lane
      float v;
      if (t == 0) v = initial[(size_t)(r0+row)*64 + lane];
      else        v = __hip_atomic_load(&pin[(size_t)(r0+row)*64 + lane],
                                        __ATOMIC_RELAXED, AGENT);
      predT[lane][row] = v;
      if (tile == 0 && t > 0)
        dout[((size_t)(r0+row)*96 + (t-1))*64 + lane] = v + bop;
    }
    if (tile == 1){
#pragma unroll
      for (int i=0;i<4;i++)
        __hip_atomic_store(&pout[(size_t)r0*64 + i*512 + tid], 0.f,
                           __ATOMIC_RELAXED, AGENT);
    }
    __syncthreads();

    float acc[8];
#pragma unroll
    for (int r=0;r<8;r++) acc[r] = ctxv[r] + (t ? cvx : 0.f);
#pragma unroll 2
    for (int o=0;o<64;o++){
      float w = w_in2[(size_t)o*4096 + jx];
      const float4* pp = (const float4*)&predT[o][rb8];
      float4 p0 = pp[0], p1 = pp[1];
      acc[0] += p0.x*w; acc[1] += p0.y*w; acc[2] += p0.z*w; acc[3] += p0.w*w;
      acc[4] += p1.x*w; acc[5] += p1.y*w; acc[6] += p1.z*w; acc[7] += p1.w*w;
    }
    float xv[8];
#pragma unroll
    for (int r=0;r<8;r++){
      float v = acc[r]*cw + cb;
      xv[r] = v * sigf(v);
      xT[half*64+lane][rb8+r] = xv[r];
    }
    __syncthreads();

    {  // xdbc partials: thread covers 4 rows x 3 n over full tile K=128
      float f0[4]={0,0,0,0}, f1[4]={0,0,0,0}, f2[4]={0,0,0,0};
#pragma unroll 4
      for (int k=0;k<128;k++){
        const float* wxp = &w_x[(size_t)(tile*128+k)*192 + lane];
        float w0 = wxp[0], w1 = wxp[64], w2 = wxp[128];
        float4 xk = *(const float4*)&xT[k][rq*4];
        f0[0]+=xk.x*w0; f0[1]+=xk.y*w0; f0[2]+=xk.z*w0; f0[3]+=xk.w*w0;
        f1[0]+=xk.x*w1; f1[1]+=xk.y*w1; f1[2]+=xk.z*w1; f1[3]+=xk.w*w1;
        f2[0]+=xk.x*w2; f2[1]+=xk.y*w2; f2[2]+=xk.z*w2; f2[3]+=xk.w*w2;
      }
#pragma unroll
      for (int r=0;r<4;r++){
        size_t base = (size_t)(r0+rq*4+r)*192 + lane;
        atomicAdd(&xdc[base      ], f0[r]);
        atomicAdd(&xdc[base +  64], f1[r]);
        atomicAdd(&xdc[base + 128], f2[r]);
      }
    }
    gbar(flag, 16*(2*t+1));

    // ---- Phase C: dt, bc, z, y, pred partials ----
#pragma unroll
    for (int i=0;i<4;i++){
      int row = i*8 + rq;                 // o == lane
      xT[lane][row] = __hip_atomic_load(&xdc[(size_t)(r0+row)*192 + lane],
                                        __ATOMIC_RELAXED, AGENT);
    }
    if (half == 0){  // bc for 32 rows: lane=n, wave wq covers 8 rows
#pragma unroll
      for (int r=0;r<8;r++){
        int row = r0 + wq*8 + r;
        float Bv = __hip_atomic_load(&xdc[(size_t)row*192 +  64 + lane],
                                     __ATOMIC_RELAXED, AGENT);
        float Cv = __hip_atomic_load(&xdc[(size_t)row*192 + 128 + lane],
                                     __ATOMIC_RELAXED, AGENT);
        float p = Bv*Cv;
#pragma unroll
        for (int s=1; s<64; s<<=1) p += __shfl_xor(p, s, 64);
        if (lane == 0) bcL[wq*8+r] = p;
      }
    }
    if (tile == 1){
#pragma unroll
      for (int i=0;i<12;i++)
        __hip_atomic_store(&xdn[(size_t)r0*192 + i*512 + tid], 0.f,
                           __ATOMIC_RELAXED, AGENT);
    }
    __syncthreads();

    float zacc[8];
#pragma unroll
    for (int r=0;r<8;r++) zacc[r] = ctzv[r] + (t ? cvz : 0.f);
#pragma unroll 2
    for (int o=0;o<64;o++){
      float w = w_in2[(size_t)o*4096 + jz];
      const float4* pp = (const float4*)&predT[o][rb8];
      float4 p0 = pp[0], p1 = pp[1];
      zacc[0] += p0.x*w; zacc[1] += p0.y*w; zacc[2] += p0.z*w; zacc[3] += p0.w*w;
      zacc[4] += p1.x*w; zacc[5] += p1.y*w; zacc[6] += p1.z*w; zacc[7] += p1.w*w;
    }
    float dacc[8];
#pragma unroll
    for (int r=0;r<8;r++) dacc[r] = 0.f;
#pragma unroll 2
    for (int o=0;o<64;o++){
      float w = w_dt[(size_t)o*2048 + jx];
      const float4* xp = (const float4*)&xT[o][rb8];
      float4 x0 = xp[0], x1 = xp[1];
      dacc[0] += x0.x*w; dacc[1] += x0.y*w; dacc[2] += x0.z*w; dacc[3] += x0.w*w;
      dacc[4] += x1.x*w; dacc[5] += x1.y*w; dacc[6] += x1.z*w; dacc[7] += x1.w*w;
    }
#pragma unroll
    for (int r=0;r<8;r++){
      float zs = zacc[r]*sigf(zacc[r]);
      float v = dacc[r] + bdt;
      float dt = (v > 15.f) ? v : __logf(1.f + __expf(v));
      float y = (dt*bcL[rb8+r] + dsk) * xv[r] * zs;
      yT[half*64+lane][rb8+r] = y;
    }
    __syncthreads();

    {  // pred partial: thread covers 4 rows x o=lane over full tile K=128
      float pacc[4]={0,0,0,0};
#pragma unroll 4
      for (int k=0;k<128;k++){
        float w = W_op[(size_t)(tile*128+k)*64 + lane];
        float4 yk = *(const float4*)&yT[k][rq*4];
        pacc[0]+=yk.x*w; pacc[1]+=yk.y*w; pacc[2]+=yk.z*w; pacc[3]+=yk.w*w;
      }
#pragma unroll
      for (int r=0;r<4;r++)
        atomicAdd(&pout[(size_t)(r0+rq*4+r)*64 + lane], pacc[r]);
    }
    gbar(flag, 16*(2*t+2));
  }

  // final step's pred -> d_out (t=95 is odd -> OUT(95) = pa0)
  if (tile == 0){
#pragma unroll
    for (int i=0;i<4;i++){
      int row = i*8 + rq;
      float v = __hip_atomic_load(&pa0[(size_t)(r0+row)*64 + lane],
                                  __ATOMIC_RELAXED, AGENT);
      dout[((size_t)(r0+row)*96 + 95)*64 + lane] = v + bop;
    }
  }
}

// ---------------- launch ----------------

extern "C" void kernel_launch(void* const* d_in, const int* in_sizes, int n_in,
                              void* d_out, int out_size, void* d_ws, size_t ws_size,
                              hipStream_t stream)
{
  const float* context = (const float*)d_in[0];
  const float* initial = (const float*)d_in[1];
  const float* w_in    = (const float*)d_in[2];
  const float* b_in    = (const float*)d_in[3];
  const float* conv_w  = (const float*)d_in[4];
  const float* conv_b  = (const float*)d_in[5];
  const float* w_x     = (const float*)d_in[6];
  const float* w_dt    = (const float*)d_in[7];
  const float* b_dt    = (const float*)d_in[8];
  // d_in[9] = A_log (unused: L=1, h0=0)
  const float* D_skip  = (const float*)d_in[10];
  const float* w_out   = (const float*)d_in[11];
  const float* b_out   = (const float*)d_in[12];
  const float* w_proj  = (const float*)d_in[13];
  const float* b_proj  = (const float*)d_in[14];

  float* ws = (float*)d_ws;
  float* ctx_xz = ws;                    // 2,097,152
  float* cvec   = ctx_xz + 2097152;      // 4,096
  float* W_op   = cvec + 4096;           // 131,072
  float* b_op   = W_op + 131072;         // 128
  float* xd0    = b_op + 128;            // 98,304
  int*   flags  = (int*)(xd0 + 98304);   // 512 ints (zeroed with xd0)
  float* xd1    = xd0 + 98304 + 512;     // 98,304
  float* pa0    = xd1 + 98304;           // 32,768
  float* pa1    = pa0 + 32768;           // 32,768
  float* dout   = (float*)d_out;

  const float* w_in2 = w_in + (size_t)1024*4096;

  k_wop <<<dim3(513),   256, 0, stream>>>(w_out, w_proj, b_out, b_proj, W_op, b_op);
  k_cvec<<<dim3(16),    256, 0, stream>>>(b_op, w_in2, cvec);
  k_ctx <<<dim3(16,32), 256, 0, stream>>>(context, w_in, b_in, ctx_xz);
  k_zero<<<dim3(387),   256, 0, stream>>>(xd0, 98304 + 512);  // xd0 + flags

  k_steps<<<dim3(256), 512, 0, stream>>>(ctx_xz, cvec, w_in2, conv_w, conv_b,
                                         w_x, w_dt, b_dt, D_skip, W_op, b_op,
                                         initial, xd0, xd1, pa0, pa1,
                                         flags, dout);
}